// Round 5
// baseline (468.210 us; speedup 1.0000x reference)
//
#include <hip/hip_runtime.h>

// ---- types ----
typedef _Float16 f16;
typedef _Float16 f16x8 __attribute__((ext_vector_type(8)));
typedef _Float16 f16x4 __attribute__((ext_vector_type(4)));
typedef float    f32x4 __attribute__((ext_vector_type(4)));

// ---- problem constants ----
constexpr int NB   = 8;      // batch
constexpr int T    = 2048;   // Tx = Tz
constexpr int D    = 1024;   // Dx = Dz = Datt = Dout
// S storage: causal 256-row bands, band b2 has (b2+1)*256 cols, packed.
constexpr int SA_BATCH = 36 * 65536;

// async global->LDS, 16B per lane; LDS dest = wave-uniform base + lane*16
__device__ __forceinline__ void load_lds16(const f16* g, f16* l) {
    __builtin_amdgcn_global_load_lds(
        (const __attribute__((address_space(1))) void*)g,
        (__attribute__((address_space(3))) void*)l, 16, 0, 0);
}

#define WAITV(N) asm volatile("s_waitcnt vmcnt(" #N ")" ::: "memory")
#define BAR2()  do { __builtin_amdgcn_s_barrier(); \
                     __builtin_amdgcn_sched_barrier(0); } while (0)

// =====================================================================
// Weight cast + transpose: W[k][n] fp32 -> Wt[n][k] f16   (3 matrices)
// =====================================================================
__global__ __launch_bounds__(256) void cast_transpose_w(
    const float* __restrict__ W0, const float* __restrict__ W1,
    const float* __restrict__ W2, f16* __restrict__ Wt)
{
    __shared__ f16 tile[32][33];
    const int which = blockIdx.z;
    const float* W = which == 0 ? W0 : (which == 1 ? W1 : W2);
    f16* dst = Wt + (size_t)which * D * D;
    const int c0 = blockIdx.x * 32, r0 = blockIdx.y * 32;
    const int tx = threadIdx.x & 31, ty = threadIdx.x >> 5;
    #pragma unroll
    for (int i = 0; i < 32; i += 8)
        tile[ty + i][tx] = (f16)W[(size_t)(r0 + ty + i) * D + c0 + tx];
    __syncthreads();
    #pragma unroll
    for (int i = 0; i < 32; i += 8)
        dst[(size_t)(c0 + ty + i) * D + r0 + tx] = tile[tx][ty + i];
}

// =====================================================================
// x,z fp32 -> f16 (elementwise, vectorized)
// =====================================================================
__global__ __launch_bounds__(256) void cast_xz(
    const float* __restrict__ x, const float* __restrict__ z,
    f16* __restrict__ xh, f16* __restrict__ zh)
{
    const float* src = blockIdx.y ? z : x;
    f16* dst = blockIdx.y ? zh : xh;
    const size_t i = ((size_t)blockIdx.x * 256 + threadIdx.x) * 4;
    const float4 v = *(const float4*)(src + i);
    f16x4 u = { (f16)v.x, (f16)v.y, (f16)v.z, (f16)v.w };
    *(f16x4*)(dst + i) = u;
}

// =====================================================================
// NT GEMM, BMx256 tile (BM=256 modes 0/4, BM=128 modes 1/2), BK=64,
// 512 threads (8 waves, 2Mx4N, per-wave (BM/2)x64).
//
// 8-PHASE SCHEDULE (T3+T4+T5, m201 port).  Stage unit = K-half:
//   S0=A[k0:32], S1=B[k0:32], S2=A[k32:64], S3=B[k32:64]; LDS panels
//   [db][kh][rows][32] f16.  Per K-tile t (db=t&1), 4 phases (ks,mhalf):
//   ph0: read av-lo(ks0)+bv(ks0) | stage S2(t+1) | BAR | 16 MFMA | BAR
//   ph1: read av-hi(ks0)         | stage S3(t+1) | vmcnt(8) | BAR | MFMA | BAR
//   ph2: read av-lo(ks1)+bv(ks1) | stage S0(t+2) | BAR | MFMA | BAR
//   ph3: read av-hi(ks1)         | stage S1(t+2) | vmcnt(8) | BAR | MFMA | BAR
//   Ledger: vmcnt(8) at ph1 certifies S2,S3(t) (read ph2/3); at ph3
//   certifies S0,S1(t+1) (read next ph0/1).  4 half-tiles permanently in
//   flight; each staged 5 phases before first read.  Tail counts derived
//   (8/4/0; 6/3/0 for BM=128).  All LDS WAR hazards sit >=1 closing
//   barrier after the last reader's lgkmcnt (checked per region).
// Chunk swizzle (2-way, free): phys chunk = logical ^ ((row>>1)&3);
// linear gload_lds dest + pre-swizzled global source + same XOR on reads.
// MODE 0: Q proj   A=xh, B=Wt(q), +bq, C f16 [M][N]      (+XCD swizzle)
// MODE 4: KV proj  A=zh, B=[Wk|Wv]t; bx<4 -> Kh; bx>=4 -> Vt transposed
// MODE 1: S        A=Qh[b], B=Kh[b]; 576 tiles (72/batch, 128Mx256N),
//                  XCD-chunked; UNNORMALIZED p=exp(S/32) into causal
//                  band layout + fp32 row sums via atomics
// MODE 2: y=P@V/r  A=band (lda=K=(by/2+1)*256), B=Vt[b]; LPT order;
//                  /rsum epilogue; C fp32
// =====================================================================
template<int MODE>
__global__ __launch_bounds__(512, 2) void gemm_nt(
    const f16* __restrict__ Ag_, const f16* __restrict__ Bg_,
    void* __restrict__ Cg_, void* __restrict__ Cg2_,
    const float* __restrict__ bias, const float* __restrict__ bias2,
    float* __restrict__ rsum)
{
    constexpr int BM  = (MODE == 1 || MODE == 2) ? 128 : 256;
    constexpr int MR  = BM / 32;        // m-frags per wave
    constexpr int MR2 = MR / 2;
    constexpr int AI  = BM / 128;       // gload insts per A k-half

    __shared__ f16 Al[4 * BM * 32];     // [db][kh][BM][32]
    __shared__ f16 Bl[4 * 256 * 32];

    int bx, by, bz = blockIdx.z;
    if (MODE == 1) {
        const int p = blockIdx.x;       // 576 = 8 XCD-chunks of 72
        bz = p & 7;
        const int u = p >> 3;
        int cnt = 1, acc0 = 0; by = 0;
        while (acc0 + cnt <= u) { acc0 += cnt; ++by; cnt = (by >> 1) + 1; }
        bx = u - acc0;
    } else if (MODE == 2) {
        const int xx = blockIdx.x;
        bz = xx & 7; bx = xx >> 3;
        by = 15 - (int)blockIdx.y;      // LPT: longest K first
    } else {
        constexpr int GX  = (MODE == 0) ? 4 : 8;
        constexpr int LGX = (MODE == 0) ? 2 : 3;
        constexpr int NWG = GX * 64;
        int id = (int)blockIdx.y * GX + (int)blockIdx.x;
        id = (id & 7) * (NWG >> 3) + (id >> 3);
        bx = id & (GX - 1);
        by = id >> LGX;
    }

    const size_t bm0 = (size_t)by * BM, bn0 = (size_t)bx * 256;
    const f16* Abase; const f16* Bbase;
    int lda, ldb, K;
    if (MODE == 0 || MODE == 4) {
        Abase = Ag_ + bm0 * D;                       lda = D;
        Bbase = Bg_ + bn0 * D;                       ldb = D; K = D;
    } else if (MODE == 1) {
        Abase = Ag_ + (size_t)bz * T * D + bm0 * D;  lda = D;
        Bbase = Bg_ + (size_t)bz * T * D + bn0 * D;  ldb = D; K = D;
    } else {
        const int by2 = by >> 1;
        K = (by2 + 1) * 256; lda = K;
        Abase = Ag_ + (size_t)bz * SA_BATCH + (size_t)(by2 * (by2 + 1) / 2) * 65536
              + (size_t)((by & 1) * 128) * K;
        Bbase = Bg_ + (size_t)bz * D * T + bn0 * T;  ldb = T;
    }

    const int t    = threadIdx.x;
    const int lane = t & 63, wave = t >> 6;
    const int wr   = (wave >> 2) * (BM / 2), wc = (wave & 3) * 64;
    const int fr   = lane & 15;
    // read-side chunk swizzle: logical chunk ho=lane>>4, phys = ho^((row>>1)&3);
    // row = 16-aligned + fr  =>  (row>>1)&3 == (fr>>1)&3 == (lane>>1)&3
    const int csw  = (((lane >> 4) ^ ((lane >> 1) & 3)) << 3);
    // staging map: one inst covers 128 rows x 32 cols; lane t: phys row t>>2,
    // phys chunk t&3; source col = (logical chunk)*8 = ((t&3)^((t>>3)&3))*8
    const int sr   = t >> 2;
    const int sc   = (((t & 3) ^ ((t >> 3) & 3)) << 3);
    const int wub  = wave * 512;         // f16 offset inside a 4096-f16 inst block
    const f16* ApS = Abase + (size_t)sr * lda + sc;
    const f16* BpS = Bbase + (size_t)sr * ldb + sc;

    f32x4 acc[MR][4] = {};
    const int nk = K >> 6;               // K-tiles (>= 4 in all modes)

    auto stageA = [&](int kt, int h, int db) {
        const size_t k = (size_t)kt * 64 + h * 32;
        #pragma unroll
        for (int j = 0; j < AI; ++j)
            load_lds16(ApS + k + (size_t)(j * 128) * lda,
                       Al + ((db * 2 + h) * BM + j * 128) * 32 + wub);
    };
    auto stageB = [&](int kt, int h, int db) {
        const size_t k = (size_t)kt * 64 + h * 32;
        #pragma unroll
        for (int j = 0; j < 2; ++j)
            load_lds16(BpS + k + (size_t)(j * 128) * ldb,
                       Bl + ((db * 2 + h) * 256 + j * 128) * 32 + wub);
    };

    // ---- prologue: S0..S3(0), S0,S1(1); certify S0,S1(0) ----
    stageA(0, 0, 0); stageB(0, 0, 0);
    stageA(0, 1, 0); stageB(0, 1, 0);
    if (1 < nk) { stageA(1, 0, 1); stageB(1, 0, 1); }
    if constexpr (BM == 256) WAITV(8); else WAITV(6);
    BAR2();

    for (int tk = 0; tk < nk; ++tk) {
        const int db = tk & 1, dn = db ^ 1;
        const f16* A0 = Al + (db * 2 + 0) * BM * 32;
        const f16* A1 = Al + (db * 2 + 1) * BM * 32;
        const f16* B0 = Bl + (db * 2 + 0) * 256 * 32;
        const f16* B1 = Bl + (db * 2 + 1) * 256 * 32;
        f16x8 av[MR2], bv[4];

        // ---------------- phase 0: ks0, m-lo ----------------
        #pragma unroll
        for (int i = 0; i < MR2; ++i)
            av[i] = *(const f16x8*)&A0[(wr + i * 16 + fr) * 32 + csw];
        #pragma unroll
        for (int j = 0; j < 4; ++j)
            bv[j] = *(const f16x8*)&B0[(wc + j * 16 + fr) * 32 + csw];
        if (tk + 1 < nk) stageA(tk + 1, 1, dn);          // S2(t+1)
        BAR2();
        __builtin_amdgcn_s_setprio(1);
        #pragma unroll
        for (int i = 0; i < MR2; ++i)
            #pragma unroll
            for (int j = 0; j < 4; ++j)
                acc[i][j] = __builtin_amdgcn_mfma_f32_16x16x32_f16(av[i], bv[j], acc[i][j], 0, 0, 0);
        __builtin_amdgcn_s_setprio(0);
        BAR2();

        // ---------------- phase 1: ks0, m-hi ----------------
        #pragma unroll
        for (int i = 0; i < MR2; ++i)
            av[i] = *(const f16x8*)&A0[(wr + (MR2 + i) * 16 + fr) * 32 + csw];
        if (tk + 1 < nk) stageB(tk + 1, 1, dn);          // S3(t+1)
        if (tk + 1 < nk) { if constexpr (BM == 256) WAITV(8); else WAITV(6); }
        else WAITV(0);
        BAR2();
        __builtin_amdgcn_s_setprio(1);
        #pragma unroll
        for (int i = 0; i < MR2; ++i)
            #pragma unroll
            for (int j = 0; j < 4; ++j)
                acc[MR2 + i][j] = __builtin_amdgcn_mfma_f32_16x16x32_f16(av[i], bv[j], acc[MR2 + i][j], 0, 0, 0);
        __builtin_amdgcn_s_setprio(0);
        BAR2();

        // ---------------- phase 2: ks1, m-lo ----------------
        #pragma unroll
        for (int i = 0; i < MR2; ++i)
            av[i] = *(const f16x8*)&A1[(wr + i * 16 + fr) * 32 + csw];
        #pragma unroll
        for (int j = 0; j < 4; ++j)
            bv[j] = *(const f16x8*)&B1[(wc + j * 16 + fr) * 32 + csw];
        if (tk + 2 < nk) stageA(tk + 2, 0, db);          // S0(t+2)
        BAR2();
        __builtin_amdgcn_s_setprio(1);
        #pragma unroll
        for (int i = 0; i < MR2; ++i)
            #pragma unroll
            for (int j = 0; j < 4; ++j)
                acc[i][j] = __builtin_amdgcn_mfma_f32_16x16x32_f16(av[i], bv[j], acc[i][j], 0, 0, 0);
        __builtin_amdgcn_s_setprio(0);
        BAR2();

        // ---------------- phase 3: ks1, m-hi ----------------
        #pragma unroll
        for (int i = 0; i < MR2; ++i)
            av[i] = *(const f16x8*)&A1[(wr + (MR2 + i) * 16 + fr) * 32 + csw];
        if (tk + 2 < nk) stageB(tk + 2, 0, db);          // S1(t+2)
        if (tk + 2 < nk)      { if constexpr (BM == 256) WAITV(8); else WAITV(6); }
        else if (tk + 1 < nk) { if constexpr (BM == 256) WAITV(4); else WAITV(3); }
        else WAITV(0);
        BAR2();
        __builtin_amdgcn_s_setprio(1);
        #pragma unroll
        for (int i = 0; i < MR2; ++i)
            #pragma unroll
            for (int j = 0; j < 4; ++j)
                acc[MR2 + i][j] = __builtin_amdgcn_mfma_f32_16x16x32_f16(av[i], bv[j], acc[MR2 + i][j], 0, 0, 0);
        __builtin_amdgcn_s_setprio(0);
        BAR2();
    }

    // ---- epilogue.  C/D map: col = lane&15, row = (lane>>4)*4 + reg ----
    const int cr = (lane >> 4) * 4, cc = lane & 15;
    if (MODE == 0) {
        f16* Cp = (f16*)Cg_;
        #pragma unroll
        for (int j = 0; j < 4; ++j) {
            const int col = (int)bn0 + wc + j * 16 + cc;
            const float bb = bias[col];
            #pragma unroll
            for (int i = 0; i < MR; ++i)
                #pragma unroll
                for (int g = 0; g < 4; ++g)
                    Cp[(bm0 + wr + i * 16 + cr + g) * D + col] = (f16)(acc[i][j][g] + bb);
        }
    } else if (MODE == 4) {
        if (bx < 4) {
            f16* Cp = (f16*)Cg_;
            #pragma unroll
            for (int j = 0; j < 4; ++j) {
                const int col = (int)bn0 + wc + j * 16 + cc;
                const float bb = bias[col];
                #pragma unroll
                for (int i = 0; i < MR; ++i)
                    #pragma unroll
                    for (int g = 0; g < 4; ++g)
                        Cp[(bm0 + wr + i * 16 + cr + g) * D + col] = (f16)(acc[i][j][g] + bb);
            }
        } else {
            f16* Vt = (f16*)Cg2_;
            const int b  = (int)(bm0 >> 11);
            const int r0 = (int)(bm0 & 2047);
            #pragma unroll
            for (int j = 0; j < 4; ++j) {
                const int colv = (int)bn0 - 1024 + wc + j * 16 + cc;
                const float bb = bias2[colv];
                #pragma unroll
                for (int i = 0; i < MR; ++i) {
                    f16x4 pk = { (f16)(acc[i][j][0] + bb), (f16)(acc[i][j][1] + bb),
                                 (f16)(acc[i][j][2] + bb), (f16)(acc[i][j][3] + bb) };
                    *(f16x4*)&Vt[(size_t)b * D * T + (size_t)colv * T + r0 + wr + i * 16 + cr] = pk;
                }
            }
        }
    } else if (MODE == 1) {
        const int by2  = by >> 1;
        const int ldab = (by2 + 1) * 256;
        f16* Cp = (f16*)Cg_ + (size_t)bz * SA_BATCH
                + (size_t)(by2 * (by2 + 1) / 2) * 65536
                + (size_t)((by & 1) * 128) * ldab + bn0;
        float* rs = rsum + (size_t)bz * T + bm0;
        #pragma unroll
        for (int i = 0; i < MR; ++i) {
            float rowsum[4] = {};
            #pragma unroll
            for (int j = 0; j < 4; ++j)
                #pragma unroll
                for (int g = 0; g < 4; ++g) {
                    const int lr = wr + i * 16 + cr + g, lc = wc + j * 16 + cc;
                    const int r = (int)bm0 + lr, c = (int)bn0 + lc;
                    const float p = (c > r) ? 0.0f : __expf(acc[i][j][g] * 0.03125f);
                    Cp[(size_t)lr * ldab + lc] = (f16)p;
                    rowsum[g] += p;
                }
            #pragma unroll
            for (int g = 0; g < 4; ++g) {
                float sv = rowsum[g];
                sv += __shfl_xor(sv, 1, 64);
                sv += __shfl_xor(sv, 2, 64);
                sv += __shfl_xor(sv, 4, 64);
                sv += __shfl_xor(sv, 8, 64);
                if (cc == 0) atomicAdd(&rs[wr + i * 16 + cr + g], sv);
            }
        }
    } else {
        float* Cp = (float*)Cg_ + (size_t)bz * T * D;
        const float* rs = rsum + (size_t)bz * T;
        #pragma unroll
        for (int i = 0; i < MR; ++i) {
            const int r4 = (int)bm0 + wr + i * 16 + cr;
            float rinv[4];
            #pragma unroll
            for (int g = 0; g < 4; ++g) rinv[g] = 1.0f / rs[r4 + g];
            #pragma unroll
            for (int j = 0; j < 4; ++j)
                #pragma unroll
                for (int g = 0; g < 4; ++g)
                    Cp[(size_t)(r4 + g) * D + bn0 + wc + j * 16 + cc] = acc[i][j][g] * rinv[g];
        }
    }
}

// =====================================================================
// launch
// =====================================================================
extern "C" void kernel_launch(void* const* d_in, const int* in_sizes, int n_in,
                              void* d_out, int out_size, void* d_ws, size_t ws_size,
                              hipStream_t stream)
{
    const float* x  = (const float*)d_in[0];
    const float* z  = (const float*)d_in[1];
    const float* Wq = (const float*)d_in[2];
    const float* bq = (const float*)d_in[3];
    const float* Wk = (const float*)d_in[4];
    const float* bk = (const float*)d_in[5];
    const float* Wv = (const float*)d_in[6];
    const float* bv = (const float*)d_in[7];
    // d_in[8] = mask: fixed causal lower-triangular, baked in.
    float* out = (float*)d_out;

    char* ws = (char*)d_ws;
    // ws layout (MiB): Wt 0-6 | xh 6-38 | zh 38-70 | Qh 70-102 |
    //                  Kh 102-134 | Vt 134-166 | rsum 200+
    // SA (36 MiB, causal bands) OVERLAPS xh + head of zh: xh is dead after
    // gemm<0>, zh dead after gemm<4>, SA written in gemm<1> (runs after).
    f16*   Wt   = (f16*)(ws);
    f16*   xh   = (f16*)(ws + 6291456ull);
    f16*   zh   = (f16*)(ws + 39845888ull);
    f16*   Qh   = (f16*)(ws + 73400320ull);
    f16*   Kh   = (f16*)(ws + 106954752ull);
    f16*   Vt   = (f16*)(ws + 140509184ull);
    f16*   SA   = (f16*)(ws + 6291456ull);        // overlap, see above
    float* rsum = (float*)(ws + 209715200ull);

    hipMemsetAsync(rsum, 0, (size_t)NB * T * sizeof(float), stream);
    cast_transpose_w<<<dim3(32, 32, 3), 256, 0, stream>>>(Wq, Wk, Wv, Wt);
    cast_xz<<<dim3(16384, 2, 1), 256, 0, stream>>>(x, z, xh, zh);
    gemm_nt<0><<<dim3(4, 64, 1), 512, 0, stream>>>(xh, Wt, Qh, nullptr, bq, nullptr, nullptr);
    gemm_nt<4><<<dim3(8, 64, 1), 512, 0, stream>>>(zh, Wt + 1048576, Kh, Vt, bk, bv, nullptr);
    gemm_nt<1><<<dim3(576, 1, 1), 512, 0, stream>>>(Qh, Kh, SA, nullptr, nullptr, nullptr, rsum);
    gemm_nt<2><<<dim3(32, 16, 1), 512, 0, stream>>>(SA, Vt, out, nullptr, nullptr, nullptr, rsum);
}

// Round 6
// 445.525 us; speedup vs baseline: 1.0509x; 1.0509x over previous
//
#include <hip/hip_runtime.h>

// ---- types ----
typedef _Float16 f16;
typedef _Float16 f16x8 __attribute__((ext_vector_type(8)));
typedef _Float16 f16x4 __attribute__((ext_vector_type(4)));
typedef float    f32x4 __attribute__((ext_vector_type(4)));

// ---- problem constants ----
constexpr int NB   = 8;      // batch
constexpr int T    = 2048;   // Tx = Tz
constexpr int D    = 1024;   // Dx = Dz = Datt = Dout
// S storage: causal 256-row bands, band b2 has (b2+1)*256 cols, packed.
constexpr int SA_BATCH = 36 * 65536;

// async global->LDS, 16B per lane; LDS dest = wave-uniform base + lane*16
__device__ __forceinline__ void load_lds16(const f16* g, f16* l) {
    __builtin_amdgcn_global_load_lds(
        (const __attribute__((address_space(1))) void*)g,
        (__attribute__((address_space(3))) void*)l, 16, 0, 0);
}

#define WAITV(N) asm volatile("s_waitcnt vmcnt(" #N ")" ::: "memory")

// =====================================================================
// Weight cast + transpose: W[k][n] fp32 -> Wt[n][k] f16   (3 matrices)
// =====================================================================
__global__ __launch_bounds__(256) void cast_transpose_w(
    const float* __restrict__ W0, const float* __restrict__ W1,
    const float* __restrict__ W2, f16* __restrict__ Wt)
{
    __shared__ f16 tile[32][33];
    const int which = blockIdx.z;
    const float* W = which == 0 ? W0 : (which == 1 ? W1 : W2);
    f16* dst = Wt + (size_t)which * D * D;
    const int c0 = blockIdx.x * 32, r0 = blockIdx.y * 32;
    const int tx = threadIdx.x & 31, ty = threadIdx.x >> 5;
    #pragma unroll
    for (int i = 0; i < 32; i += 8)
        tile[ty + i][tx] = (f16)W[(size_t)(r0 + ty + i) * D + c0 + tx];
    __syncthreads();
    #pragma unroll
    for (int i = 0; i < 32; i += 8)
        dst[(size_t)(c0 + ty + i) * D + r0 + tx] = tile[tx][ty + i];
}

// =====================================================================
// x,z fp32 -> f16 (elementwise, vectorized)
// =====================================================================
__global__ __launch_bounds__(256) void cast_xz(
    const float* __restrict__ x, const float* __restrict__ z,
    f16* __restrict__ xh, f16* __restrict__ zh)
{
    const float* src = blockIdx.y ? z : x;
    f16* dst = blockIdx.y ? zh : xh;
    const size_t i = ((size_t)blockIdx.x * 256 + threadIdx.x) * 4;
    const float4 v = *(const float4*)(src + i);
    f16x4 u = { (f16)v.x, (f16)v.y, (f16)v.z, (f16)v.w };
    *(f16x4*)(dst + i) = u;
}

// =====================================================================
// NT GEMM, BMx256 tile (BM=256 modes 0/4, BM=128 modes 1/2), BK=64,
// 512 threads (8 waves, 2Mx4N, per-wave (BM/2)x64).  2-buffer ring,
// counted-vmcnt pipeline: stage(s+1) -> vmcnt(SLOADS) [retires tile s's
// loads, tile s+1 stays in flight across both barriers] -> s_barrier ->
// ALL fragment reads (both ks halves) -> MFMA clusters -> s_barrier.
// Reads are hoisted before any MFMA and NO setprio/sched fences inside
// the compute region, so the compiler's counted lgkmcnt interleaves
// ks1 ds_reads under ks0 MFMAs (LDS pipe overlaps MFMA pipe per wave).
// Bank-conflict swizzle (both-sides): linear gload_lds dest, global
// SOURCE pre-swizzled chunk = (t&7)^((t>>3)&7), fragment reads XOR fr&7.
// MODE 0: Q proj   A=xh, B=Wt(q), +bq, C f16 [M][N]      (+XCD swizzle)
// MODE 4: KV proj  A=zh, B=[Wk|Wv]t; bx<4 -> Kh; bx>=4 -> Vt transposed
// MODE 1: S        A=Qh[b], B=Kh[b]; 576 tiles (72/batch, 128Mx256N),
//                  XCD-chunked; UNNORMALIZED p=exp(S/32) into causal
//                  band layout + fp32 row sums via atomics
// MODE 2: y=P@V/r  A=band (lda=K=(by/2+1)*256), B=Vt[b]; LPT order;
//                  /rsum epilogue; C fp32
// =====================================================================
template<int MODE>
__global__ __launch_bounds__(512, 2) void gemm_nt(
    const f16* __restrict__ Ag_, const f16* __restrict__ Bg_,
    void* __restrict__ Cg_, void* __restrict__ Cg2_,
    const float* __restrict__ bias, const float* __restrict__ bias2,
    float* __restrict__ rsum)
{
    constexpr int BM     = (MODE == 1 || MODE == 2) ? 128 : 256;
    constexpr int MR     = BM / 32;        // fragment rows per wave
    constexpr int ALOADS = BM / 64;        // gload_lds per A K-tile
    constexpr int SLOADS = ALOADS + 4;     // total per stage

    __shared__ f16 As[2 * BM * 64];
    __shared__ f16 Bs[2 * 256 * 64];

    int bx, by, bz = blockIdx.z;
    if (MODE == 1) {
        const int p = blockIdx.x;       // 576 = 8 XCD-chunks of 72
        bz = p & 7;
        const int u = p >> 3;
        int cnt = 1, acc0 = 0; by = 0;
        while (acc0 + cnt <= u) { acc0 += cnt; ++by; cnt = (by >> 1) + 1; }
        bx = u - acc0;
    } else if (MODE == 2) {
        const int xx = blockIdx.x;
        bz = xx & 7; bx = xx >> 3;
        by = 15 - (int)blockIdx.y;      // LPT: longest K first
    } else {
        constexpr int GX  = (MODE == 0) ? 4 : 8;
        constexpr int LGX = (MODE == 0) ? 2 : 3;
        constexpr int NWG = GX * 64;
        int id = (int)blockIdx.y * GX + (int)blockIdx.x;
        id = (id & 7) * (NWG >> 3) + (id >> 3);
        bx = id & (GX - 1);
        by = id >> LGX;
    }

    const size_t bm0 = (size_t)by * BM, bn0 = (size_t)bx * 256;
    const f16* Abase; const f16* Bbase;
    int lda, ldb, K;
    if (MODE == 0 || MODE == 4) {
        Abase = Ag_ + bm0 * D;                       lda = D;
        Bbase = Bg_ + bn0 * D;                       ldb = D; K = D;
    } else if (MODE == 1) {
        Abase = Ag_ + (size_t)bz * T * D + bm0 * D;  lda = D;
        Bbase = Bg_ + (size_t)bz * T * D + bn0 * D;  ldb = D; K = D;
    } else {
        const int by2 = by >> 1;
        K = (by2 + 1) * 256; lda = K;
        Abase = Ag_ + (size_t)bz * SA_BATCH + (size_t)(by2 * (by2 + 1) / 2) * 65536
              + (size_t)((by & 1) * 128) * K;
        Bbase = Bg_ + (size_t)bz * D * T + bn0 * T;  ldb = T;
    }

    const int t    = threadIdx.x;
    const int lane = t & 63, wave = t >> 6;
    const int wr   = (wave >> 2) * (BM / 2), wc = (wave & 3) * 64;
    const int fr   = lane & 15, ho = lane >> 4;
    // staging map: phys chunk t&7 of row t>>3 holds logical chunk
    // (t&7)^((t>>3)&7); linear gload_lds dest + pre-swizzled source
    const int srow = t >> 3;
    const int scol = ((t & 7) ^ ((t >> 3) & 7)) * 8;
    const int wub  = wave * 512;          // f16; per-inst adds i*4096
    const f16* Ap = Abase + (size_t)srow * lda + scol;
    const f16* Bp = Bbase + (size_t)srow * ldb + scol;
    // fragment read swizzle: chunk' = chunk ^ (row&7), row&7 == fr&7
    const int fsw = fr & 7;

    f32x4 acc[MR][4] = {};
    const int nk = K >> 6;

    auto stage = [&](int s, int b) {
        const size_t k = (size_t)s * 64;
        #pragma unroll
        for (int i = 0; i < ALOADS; ++i)
            load_lds16(Ap + k + (size_t)(i * 64) * lda,
                       As + b * (BM * 64) + i * 4096 + wub);
        #pragma unroll
        for (int i = 0; i < 4; ++i)
            load_lds16(Bp + k + (size_t)(i * 64) * ldb,
                       Bs + b * 16384 + i * 4096 + wub);
    };

    stage(0, 0);

    for (int s = 0; s < nk; ++s) {
        const int cur = s & 1;
        if (s + 1 < nk) {
            stage(s + 1, cur ^ 1);                     // SLOADS in flight
            if constexpr (SLOADS == 8) WAITV(8); else WAITV(6);
        } else {
            WAITV(0);
        }
        __builtin_amdgcn_sched_barrier(0);
        __builtin_amdgcn_s_barrier();                  // publish tile s
        __builtin_amdgcn_sched_barrier(0);             // reads stay below

        const f16* Ab = As + cur * (BM * 64);
        const f16* Bb = Bs + cur * 16384;
        // ---- ALL fragment reads first (both ks), no fences after:
        // compiler's counted lgkmcnt overlaps ks1 reads with ks0 MFMAs
        f16x8 av[2][MR], bv[2][4];
        #pragma unroll
        for (int kc = 0; kc < 2; ++kc) {
            const int ch = (((kc << 2) | ho) ^ fsw) << 3;
            #pragma unroll
            for (int i = 0; i < MR; ++i)
                av[kc][i] = *(const f16x8*)&Ab[((wr + i * 16 + fr) << 6) + ch];
            #pragma unroll
            for (int j = 0; j < 4; ++j)
                bv[kc][j] = *(const f16x8*)&Bb[((wc + j * 16 + fr) << 6) + ch];
        }
        #pragma unroll
        for (int kc = 0; kc < 2; ++kc)
            #pragma unroll
            for (int i = 0; i < MR; ++i)
                #pragma unroll
                for (int j = 0; j < 4; ++j)
                    acc[i][j] = __builtin_amdgcn_mfma_f32_16x16x32_f16(
                        av[kc][i], bv[kc][j], acc[i][j], 0, 0, 0);

        __builtin_amdgcn_sched_barrier(0);             // stage stays below
        __builtin_amdgcn_s_barrier();                  // protect buf cur
    }

    // ---- epilogue.  C/D map: col = lane&15, row = (lane>>4)*4 + reg ----
    const int cr = (lane >> 4) * 4, cc = lane & 15;
    if (MODE == 0) {
        f16* Cp = (f16*)Cg_;
        #pragma unroll
        for (int j = 0; j < 4; ++j) {
            const int col = (int)bn0 + wc + j * 16 + cc;
            const float bb = bias[col];
            #pragma unroll
            for (int i = 0; i < MR; ++i)
                #pragma unroll
                for (int g = 0; g < 4; ++g)
                    Cp[(bm0 + wr + i * 16 + cr + g) * D + col] = (f16)(acc[i][j][g] + bb);
        }
    } else if (MODE == 4) {
        if (bx < 4) {
            f16* Cp = (f16*)Cg_;
            #pragma unroll
            for (int j = 0; j < 4; ++j) {
                const int col = (int)bn0 + wc + j * 16 + cc;
                const float bb = bias[col];
                #pragma unroll
                for (int i = 0; i < MR; ++i)
                    #pragma unroll
                    for (int g = 0; g < 4; ++g)
                        Cp[(bm0 + wr + i * 16 + cr + g) * D + col] = (f16)(acc[i][j][g] + bb);
            }
        } else {
            f16* Vt = (f16*)Cg2_;
            const int b  = (int)(bm0 >> 11);
            const int r0 = (int)(bm0 & 2047);
            #pragma unroll
            for (int j = 0; j < 4; ++j) {
                const int colv = (int)bn0 - 1024 + wc + j * 16 + cc;
                const float bb = bias2[colv];
                #pragma unroll
                for (int i = 0; i < MR; ++i) {
                    f16x4 pk = { (f16)(acc[i][j][0] + bb), (f16)(acc[i][j][1] + bb),
                                 (f16)(acc[i][j][2] + bb), (f16)(acc[i][j][3] + bb) };
                    *(f16x4*)&Vt[(size_t)b * D * T + (size_t)colv * T + r0 + wr + i * 16 + cr] = pk;
                }
            }
        }
    } else if (MODE == 1) {
        const int by2  = by >> 1;
        const int ldab = (by2 + 1) * 256;
        f16* Cp = (f16*)Cg_ + (size_t)bz * SA_BATCH
                + (size_t)(by2 * (by2 + 1) / 2) * 65536
                + (size_t)((by & 1) * 128) * ldab + bn0;
        float* rs = rsum + (size_t)bz * T + bm0;
        #pragma unroll
        for (int i = 0; i < MR; ++i) {
            float rowsum[4] = {};
            #pragma unroll
            for (int j = 0; j < 4; ++j)
                #pragma unroll
                for (int g = 0; g < 4; ++g) {
                    const int lr = wr + i * 16 + cr + g, lc = wc + j * 16 + cc;
                    const int r = (int)bm0 + lr, c = (int)bn0 + lc;
                    const float p = (c > r) ? 0.0f : __expf(acc[i][j][g] * 0.03125f);
                    Cp[(size_t)lr * ldab + lc] = (f16)p;
                    rowsum[g] += p;
                }
            #pragma unroll
            for (int g = 0; g < 4; ++g) {
                float sv = rowsum[g];
                sv += __shfl_xor(sv, 1, 64);
                sv += __shfl_xor(sv, 2, 64);
                sv += __shfl_xor(sv, 4, 64);
                sv += __shfl_xor(sv, 8, 64);
                if (cc == 0) atomicAdd(&rs[wr + i * 16 + cr + g], sv);
            }
        }
    } else {
        float* Cp = (float*)Cg_ + (size_t)bz * T * D;
        const float* rs = rsum + (size_t)bz * T;
        #pragma unroll
        for (int i = 0; i < MR; ++i) {
            const int r4 = (int)bm0 + wr + i * 16 + cr;
            float rinv[4];
            #pragma unroll
            for (int g = 0; g < 4; ++g) rinv[g] = 1.0f / rs[r4 + g];
            #pragma unroll
            for (int j = 0; j < 4; ++j)
                #pragma unroll
                for (int g = 0; g < 4; ++g)
                    Cp[(size_t)(r4 + g) * D + bn0 + wc + j * 16 + cc] = acc[i][j][g] * rinv[g];
        }
    }
}

// =====================================================================
// launch
// =====================================================================
extern "C" void kernel_launch(void* const* d_in, const int* in_sizes, int n_in,
                              void* d_out, int out_size, void* d_ws, size_t ws_size,
                              hipStream_t stream)
{
    const float* x  = (const float*)d_in[0];
    const float* z  = (const float*)d_in[1];
    const float* Wq = (const float*)d_in[2];
    const float* bq = (const float*)d_in[3];
    const float* Wk = (const float*)d_in[4];
    const float* bk = (const float*)d_in[5];
    const float* Wv = (const float*)d_in[6];
    const float* bv = (const float*)d_in[7];
    // d_in[8] = mask: fixed causal lower-triangular, baked in.
    float* out = (float*)d_out;

    char* ws = (char*)d_ws;
    // ws layout (MiB): Wt 0-6 | xh 6-38 | zh 38-70 | Qh 70-102 |
    //                  Kh 102-134 | Vt 134-166 | rsum 200+
    // SA (36 MiB, causal bands) OVERLAPS xh + head of zh: xh is dead after
    // gemm<0>, zh dead after gemm<4>, SA written in gemm<1> (runs after).
    f16*   Wt   = (f16*)(ws);
    f16*   xh   = (f16*)(ws + 6291456ull);
    f16*   zh   = (f16*)(ws + 39845888ull);
    f16*   Qh   = (f16*)(ws + 73400320ull);
    f16*   Kh   = (f16*)(ws + 106954752ull);
    f16*   Vt   = (f16*)(ws + 140509184ull);
    f16*   SA   = (f16*)(ws + 6291456ull);        // overlap, see above
    float* rsum = (float*)(ws + 209715200ull);

    hipMemsetAsync(rsum, 0, (size_t)NB * T * sizeof(float), stream);
    cast_transpose_w<<<dim3(32, 32, 3), 256, 0, stream>>>(Wq, Wk, Wv, Wt);
    cast_xz<<<dim3(16384, 2, 1), 256, 0, stream>>>(x, z, xh, zh);
    gemm_nt<0><<<dim3(4, 64, 1), 512, 0, stream>>>(xh, Wt, Qh, nullptr, bq, nullptr, nullptr);
    gemm_nt<4><<<dim3(8, 64, 1), 512, 0, stream>>>(zh, Wt + 1048576, Kh, Vt, bk, bv, nullptr);
    gemm_nt<1><<<dim3(576, 1, 1), 512, 0, stream>>>(Qh, Kh, SA, nullptr, nullptr, nullptr, rsum);
    gemm_nt<2><<<dim3(32, 16, 1), 512, 0, stream>>>(SA, Vt, out, nullptr, nullptr, nullptr, rsum);
}